// Round 15
// baseline (182.480 us; speedup 1.0000x reference)
//
#include <hip/hip_runtime.h>
#include <cstddef>

#define N_PIX 4096
#define HW 64
#define LOG2E 1.4426950408889634f
#define SHIFT2 28.8539008177793f   // 20 * log2(e)

typedef __attribute__((ext_vector_type(8))) short bf16x8;
typedef __attribute__((ext_vector_type(4))) float f32x4;
typedef unsigned int u32;

static __device__ __forceinline__ unsigned short f2bf(float f) {
    union { float f; unsigned u; } v; v.f = f;
    unsigned r = v.u + 0x7fffu + ((v.u >> 16) & 1u);   // RNE
    return (unsigned short)(r >> 16);
}
static __device__ __forceinline__ float bf2f(unsigned short s) {
    union { unsigned u; float f; } v; v.u = (unsigned)s << 16;
    return v.f;
}
// (bf16(hi)<<16)|bf16(lo), truncating: one v_perm_b32
static __device__ __forceinline__ unsigned pack_bf16_trunc(float lo, float hi) {
    union { float f; unsigned u; } a, b; a.f = hi; b.f = lo;
    return __builtin_amdgcn_perm(a.u, b.u, 0x07060302u);
}
// async global->LDS, 16 B per lane; LDS dest is WAVE-UNIFORM base + lane*16
static __device__ __forceinline__ void gll16(const void* g, void* l) {
    __builtin_amdgcn_global_load_lds(
        (const __attribute__((address_space(1))) u32*)g,
        (__attribute__((address_space(3))) u32*)l, 16, 0, 0);
}

// ---------------------------------------------------------------------------
// prep: z<4  -> x [b][256 ci][4096 px] fp32 -> xbf [b][4096 px][256 ci] bf16
//       z==4 -> weights -> wAll [kb][320 rows][32 kin] bf16 + zero page.
// ---------------------------------------------------------------------------
__global__ __launch_bounds__(256) void prep_kernel(
    const float* __restrict__ x, unsigned short* __restrict__ xbf,
    const float* __restrict__ wq, const float* __restrict__ wk,
    const float* __restrict__ wv, unsigned short* __restrict__ wAll,
    unsigned short* __restrict__ zp)
{
    const int tid = threadIdx.x;
    if (blockIdx.z < 4) {
        __shared__ unsigned short Ts[64][72];
        const int px0 = blockIdx.x * 64, ci0 = blockIdx.y * 64, b = blockIdx.z;
        const float* xb = x + ((size_t)b * 256 + ci0) * N_PIX;

#pragma unroll
        for (int r = 0; r < 4; ++r) {
            int c = r * 16 + (tid >> 4);
            int p4 = (tid & 15) * 4;
            float4 v = *(const float4*)&xb[(size_t)c * N_PIX + px0 + p4];
            Ts[c][p4 + 0] = f2bf(v.x);
            Ts[c][p4 + 1] = f2bf(v.y);
            Ts[c][p4 + 2] = f2bf(v.z);
            Ts[c][p4 + 3] = f2bf(v.w);
        }
        __syncthreads();
#pragma unroll
        for (int r = 0; r < 2; ++r) {
            int id = tid * 2 + r;
            int p = id >> 3, c8 = (id & 7) * 8;
            ushort4 lo, hi;
            lo.x = Ts[c8 + 0][p]; lo.y = Ts[c8 + 1][p];
            lo.z = Ts[c8 + 2][p]; lo.w = Ts[c8 + 3][p];
            hi.x = Ts[c8 + 4][p]; hi.y = Ts[c8 + 5][p];
            hi.z = Ts[c8 + 6][p]; hi.w = Ts[c8 + 7][p];
            size_t off = ((size_t)b * N_PIX + px0 + p) * 256 + ci0 + c8;
            *(ushort4*)&xbf[off]     = lo;
            *(ushort4*)&xbf[off + 4] = hi;
        }
    } else {
        const int f = blockIdx.y * 64 + blockIdx.x;        // 0..255
#pragma unroll
        for (int base = 0; base < 2; ++base) {
            int gid = base * 65536 + f * 256 + tid;
            if (gid < 256) zp[gid] = 0;
            if (gid >= 72 * 320 * 4) continue;
            int part = gid & 3;
            int m = (gid >> 2) % 320;
            int kb = gid / 1280;
            int t = kb >> 3;
            int ci0 = (kb & 7) * 32 + part * 8;
            const float* src; int co; float sc = 1.f;
            if (m < 256)      { src = wv; co = m; }
            else if (m < 288) { src = wq; co = m - 256; sc = LOG2E; }
            else              { src = wk; co = m - 288; }
            ushort4 lo, hi;
            lo.x = f2bf(sc * src[((size_t)co * 256 + ci0 + 0) * 9 + t]);
            lo.y = f2bf(sc * src[((size_t)co * 256 + ci0 + 1) * 9 + t]);
            lo.z = f2bf(sc * src[((size_t)co * 256 + ci0 + 2) * 9 + t]);
            lo.w = f2bf(sc * src[((size_t)co * 256 + ci0 + 3) * 9 + t]);
            hi.x = f2bf(sc * src[((size_t)co * 256 + ci0 + 4) * 9 + t]);
            hi.y = f2bf(sc * src[((size_t)co * 256 + ci0 + 5) * 9 + t]);
            hi.z = f2bf(sc * src[((size_t)co * 256 + ci0 + 6) * 9 + t]);
            hi.w = f2bf(sc * src[((size_t)co * 256 + ci0 + 7) * 9 + t]);
            size_t off = ((size_t)kb * 320 + m) * 32 + part * 8;
            *(ushort4*)&wAll[off]     = lo;
            *(ushort4*)&wAll[off + 4] = hi;
        }
    }
}

// ---------------------------------------------------------------------------
// Conv implicit GEMM v9 (best conv measured, R11 anchor): 64-px tile,
// 512 blocks = 2/CU, 3-buf gll-DMA pipeline, counted vmcnt(4/3), raw
// s_barrier, 72-step K-loop fully unrolled.
// ---------------------------------------------------------------------------
__global__ __launch_bounds__(256, 2) void conv_gemm_v9(
    const unsigned short* __restrict__ xbf, const unsigned short* __restrict__ wAll,
    const float* __restrict__ bq, const float* __restrict__ bk,
    const float* __restrict__ bv, const unsigned short* __restrict__ zpage,
    unsigned short* __restrict__ vbf, unsigned short* __restrict__ qt,
    unsigned short* __restrict__ kt)
{
    __shared__ unsigned short Bl[3 * 7168];   // 3 bufs x 14336 B = 43 KB

    const int tid = threadIdx.x;
    const int w = tid >> 6, lane = tid & 63, quad = lane >> 4, l15 = lane & 15;
    const int y = blockIdx.x, rh = blockIdx.y, b = blockIdx.z;
    const int rg = w >> 1;          // 80-row group within the 160
    const int pxh = w & 1;          // 32-px half

    const unsigned short* xb = xbf + (size_t)b * N_PIX * 256;
    const unsigned short* aSrc = wAll + (size_t)rh * 160 * 32;   // +kb*10240

    auto stage = [&](int kb, int buf) {
        const int t_ = kb >> 3;
        const int ty = t_ / 3;
        const int dy = ty - 1, dx = t_ - ty * 3 - 1;
        const int gy = y + dy;
        const bool rowOK = ((unsigned)gy < 64u);
        const int ci0 = (kb & 7) * 32;
        const unsigned short* aS = aSrc + (size_t)kb * 10240;
        unsigned short* tile = &Bl[buf * 7168];
#pragma unroll
        for (int r = 0; r < 4; ++r) {
            const int c = r * 4 + w;
            if (r == 3 && w >= 2) continue;      // wave-uniform skip
            if (c < 10) {
                int o = c * 1024 + lane * 16;
                int u = o ^ (((o >> 7) & 7) << 4);
                gll16(aS + (u >> 1), tile + c * 512);
            } else {
                int o = (c - 10) * 1024 + lane * 16;
                int u = o ^ (((o >> 7) & 7) << 4);
                int px = u >> 6, k16 = (u >> 4) & 3;
                int gx = px + dx;
                const unsigned short* src =
                    (rowOK && (unsigned)gx < 64u)
                        ? xb + ((size_t)(gy * 64 + gx) * 256 + ci0 + k16 * 8)
                        : zpage;
                gll16(src, tile + 5120 + (c - 10) * 512);
            }
        }
    };

    f32x4 acc[5][2];
#pragma unroll
    for (int cb = 0; cb < 5; ++cb)
#pragma unroll
        for (int jb = 0; jb < 2; ++jb) acc[cb][jb] = (f32x4){0.f, 0.f, 0.f, 0.f};

    // ---- prologue: fill pipeline 2 deep
    stage(0, 0);
    stage(1, 1);
    if (w < 2) asm volatile("s_waitcnt vmcnt(4)" ::: "memory");
    else       asm volatile("s_waitcnt vmcnt(3)" ::: "memory");
    __builtin_amdgcn_s_barrier();
    __builtin_amdgcn_sched_barrier(0);

#pragma unroll
    for (int kb = 0; kb < 72; ++kb) {
        const int buf = kb % 3;
        const int pb  = (kb + 2) % 3;
        const bool more2 = (kb + 2 < 72);
        const bool more1 = (kb + 1 < 72);
        if (more2) stage(kb + 2, pb);

        // ---- frag reads from buf (swizzled), then MFMA
        const int bb = buf * 7168;
        bf16x8 af[5], bfr[2];
#pragma unroll
        for (int cb = 0; cb < 5; ++cb) {
            int sr = rg * 80 + cb * 16 + l15;
            int u = sr * 64 + quad * 16;
            u ^= ((u >> 7) & 7) << 4;
            af[cb] = *(const bf16x8*)&Bl[bb + (u >> 1)];
        }
#pragma unroll
        for (int jb = 0; jb < 2; ++jb) {
            int px = pxh * 32 + jb * 16 + l15;
            int u = px * 64 + quad * 16;
            u ^= ((u >> 7) & 7) << 4;
            bfr[jb] = *(const bf16x8*)&Bl[bb + 5120 + (u >> 1)];
        }
        __builtin_amdgcn_s_setprio(1);
#pragma unroll
        for (int cb = 0; cb < 5; ++cb)
#pragma unroll
            for (int jb = 0; jb < 2; ++jb)
                acc[cb][jb] = __builtin_amdgcn_mfma_f32_16x16x32_bf16(
                    af[cb], bfr[jb], acc[cb][jb], 0, 0, 0);
        __builtin_amdgcn_s_setprio(0);

        // ---- counted wait: kb+1 landed, kb+2 stays in flight
        if (more2) {
            if (w < 2) asm volatile("s_waitcnt vmcnt(4)" ::: "memory");
            else       asm volatile("s_waitcnt vmcnt(3)" ::: "memory");
        } else if (more1) {
            asm volatile("s_waitcnt vmcnt(0)" ::: "memory");
        }
        if (more1) {
            __builtin_amdgcn_s_barrier();
            __builtin_amdgcn_sched_barrier(0);
        }
    }

    // ---- epilogue: rows <256 -> V, 256..287 -> Q (log2e-scaled), 288.. -> K
#pragma unroll
    for (int cb = 0; cb < 5; ++cb) {
        int cBase = rh * 160 + rg * 80 + cb * 16 + quad * 4;
#pragma unroll
        for (int r = 0; r < 4; ++r) {
            int c = cBase + r;
            if (c < 256) {
                float bias = bv[c];
#pragma unroll
                for (int jb = 0; jb < 2; ++jb) {
                    int px = y * 64 + pxh * 32 + jb * 16 + l15;
                    vbf[((size_t)b * 256 + c) * N_PIX + px] = f2bf(acc[cb][jb][r] + bias);
                }
            } else if (c < 288) {
                float bias = bq[c - 256] * LOG2E;
#pragma unroll
                for (int jb = 0; jb < 2; ++jb) {
                    int px = y * 64 + pxh * 32 + jb * 16 + l15;
                    qt[((size_t)b * N_PIX + px) * 32 + (c - 256)] = f2bf(acc[cb][jb][r] + bias);
                }
            } else {
                float bias = bk[c - 288];
#pragma unroll
                for (int jb = 0; jb < 2; ++jb) {
                    int px = y * 64 + pxh * 32 + jb * 16 + l15;
                    kt[((size_t)b * N_PIX + px) * 32 + (c - 288)] = f2bf(acc[cb][jb][r] + bias);
                }
            }
        }
    }
}

// ---------------------------------------------------------------------------
// MFMA flash attention v6 (R14 structure, LDS 50 KB): single Pfrag +
// 2 barriers/iter, per-wave coalesced V DMA, VGPR 128.  R14 showed the
// LDS diet alone didn't move occupancy because the GRID was 512 blocks =
// exactly 2/CU.  split=8 (launcher) now supplies 1024 blocks -> 3/CU
// resident (3x51200=150KB<=160KB; 3 waves/SIMD x 128 VGPR = 384 <= 512).
// ---------------------------------------------------------------------------
__global__ __launch_bounds__(256, 2) void fused_attn_mfma(
    const unsigned short* __restrict__ qt, const unsigned short* __restrict__ kt,
    const unsigned short* __restrict__ vbf,
    unsigned short* __restrict__ Abuf, float* __restrict__ lbuf, int iRange)
{
    const int tid  = threadIdx.x;
    const int w    = tid >> 6;
    const int lane = tid & 63;
    const int quad = lane >> 4;
    const int l15  = lane & 15;
    const int j0   = blockIdx.x * 128;
    const int b    = blockIdx.y;
    const int sp   = blockIdx.z;
    const int iBeg = sp * iRange;
    const int NI   = iRange / 64;

    const unsigned short* qtb = qt + (size_t)b * N_PIX * 32;
    const unsigned short* ktb = kt + (size_t)b * N_PIX * 32;
    const unsigned short* vb  = vbf + ((size_t)b * 256 + w * 64) * N_PIX;

    __shared__ unsigned Pfrag[4096];             // 16 KB single buffer
    __shared__ unsigned short Vl[4][2][2048];    // 32 KB: per-wave 2x4KB V slices
    __shared__ float lred[4][128];               // 2 KB  -> total 50 KB

    bf16x8 kf[8];
#pragma unroll
    for (int jb = 0; jb < 8; ++jb)
        kf[jb] = *(const bf16x8*)&ktb[((size_t)(j0 + jb * 16 + l15)) * 32 + quad * 8];

    f32x4 acc[4][8];
#pragma unroll
    for (int cb = 0; cb < 4; ++cb)
#pragma unroll
        for (int jb = 0; jb < 8; ++jb)
            acc[cb][jb] = (f32x4){0.f, 0.f, 0.f, 0.f};

    float lpart[8] = {0.f, 0.f, 0.f, 0.f, 0.f, 0.f, 0.f, 0.f};

    const int wFrag = w >> 1;
    const int wL    = ((w & 1) << 5) + ((quad >> 1) << 4) + l15;
    const int wEl2  = (quad & 1) << 1;   // dword offset 0 or 2

    // wave w stages V rows [w*64,+64) x cols [c0,+32) (4 KB) into Vl[w][vbuf];
    // XOR swizzle on SOURCE offset (gll dest is linear), same XOR on read.
    auto stageV = [&](int c0, int vbuf) {
#pragma unroll
        for (int r = 0; r < 4; ++r) {
            int o = r * 1024 + lane * 16;
            int u = o ^ (((o >> 7) & 7) << 4);
            const unsigned short* src =
                vb + (size_t)(u >> 6) * N_PIX + c0 + ((u & 63) >> 1);
            gll16(src, &Vl[w][vbuf][r * 512]);
        }
    };
    auto readVa = [&](int vbuf, bf16x8 (&va)[4]) {
#pragma unroll
        for (int cb = 0; cb < 4; ++cb) {
            int o = (cb * 16 + l15) * 64 + quad * 16;
            int u = o ^ (((o >> 7) & 7) << 4);
            va[cb] = *(const bf16x8*)&Vl[w][vbuf][u >> 1];
        }
    };

    auto s_phase = [&](bf16x8 qa) {
#pragma unroll
        for (int jb = 0; jb < 8; ++jb) {
            f32x4 s = __builtin_amdgcn_mfma_f32_16x16x32_bf16(
                qa, kf[jb], (f32x4){-SHIFT2, -SHIFT2, -SHIFT2, -SHIFT2}, 0, 0, 0);
            float p0 = __builtin_amdgcn_exp2f(s[0]);
            float p1 = __builtin_amdgcn_exp2f(s[1]);
            float p2 = __builtin_amdgcn_exp2f(s[2]);
            float p3 = __builtin_amdgcn_exp2f(s[3]);
            lpart[jb] += (p0 + p1) + (p2 + p3);
            unsigned u0 = pack_bf16_trunc(p0, p1);
            unsigned u1 = pack_bf16_trunc(p2, p3);
            unsigned base = (((jb << 1) + wFrag) * 64 + wL) * 4 + wEl2;
            Pfrag[base]     = u0;
            Pfrag[base + 1] = u1;
        }
    };

    auto load_qa = [&](int i0) {
        return *(const bf16x8*)&qtb[((size_t)(i0 + w * 16 + l15)) * 32 + quad * 8];
    };

    // ---- prologue: V(iter0) DMA, S(0) -> Pfrag, barrier
    stageV(iBeg, 0);
    stageV(iBeg + 32, 1);
    s_phase(load_qa(iBeg));
    asm volatile("s_waitcnt lgkmcnt(0)" ::: "memory");
    __builtin_amdgcn_s_barrier();
    __builtin_amdgcn_sched_barrier(0);

    for (int n = 0; n < NI; ++n) {
        const bool hasN = (n + 1 < NI);
        const int inext = iBeg + (n + 1) * 64;
        bf16x8 qaN;
        if (hasN) qaN = load_qa(inext);

        bf16x8 pb[8], va[4];

        // ---- ks = 0: consume Vl[w][0], refill with V(n+1, ks0)
#pragma unroll
        for (int jb = 0; jb < 8; ++jb)
            pb[jb] = *(const bf16x8*)&Pfrag[((jb << 1) * 64 + lane) * 4];
        if (hasN) asm volatile("s_waitcnt vmcnt(5)" ::: "memory");   // A landed (B4+qa1 left)
        else      asm volatile("s_waitcnt vmcnt(4)" ::: "memory");   // A landed (B4 left)
        __builtin_amdgcn_sched_barrier(0);
        readVa(0, va);
        asm volatile("s_waitcnt lgkmcnt(0)" ::: "memory");           // reads done pre-overwrite
        __builtin_amdgcn_sched_barrier(0);
        if (hasN) stageV(inext, 0);
#pragma unroll
        for (int cb = 0; cb < 4; ++cb)
#pragma unroll
            for (int jb = 0; jb < 8; ++jb)
                acc[cb][jb] = __builtin_amdgcn_mfma_f32_16x16x32_bf16(
                    va[cb], pb[jb], acc[cb][jb], 0, 0, 0);

        // ---- ks = 1: consume Vl[w][1], refill with V(n+1, ks1)
#pragma unroll
        for (int jb = 0; jb < 8; ++jb)
            pb[jb] = *(const bf16x8*)&Pfrag[(((jb << 1) + 1) * 64 + lane) * 4];
        if (hasN) asm volatile("s_waitcnt vmcnt(5)" ::: "memory");   // B landed (qa1+A'4 left)
        else      asm volatile("s_waitcnt vmcnt(0)" ::: "memory");
        __builtin_amdgcn_sched_barrier(0);
        readVa(1, va);
        asm volatile("s_waitcnt lgkmcnt(0)" ::: "memory");
        __builtin_amdgcn_sched_barrier(0);
        if (hasN) stageV(inext + 32, 1);
#pragma unroll
        for (int cb = 0; cb < 4; ++cb)
#pragma unroll
            for (int jb = 0; jb < 8; ++jb)
                acc[cb][jb] = __builtin_amdgcn_mfma_f32_16x16x32_bf16(
                    va[cb], pb[jb], acc[cb][jb], 0, 0, 0);

        // ---- release Pfrag, then S(n+1) -> Pfrag, then publish
        if (hasN) {
            asm volatile("s_waitcnt lgkmcnt(0)" ::: "memory");   // all P reads done
            __builtin_amdgcn_s_barrier();                        // #1: release
            __builtin_amdgcn_sched_barrier(0);
            s_phase(qaN);
            asm volatile("s_waitcnt lgkmcnt(0)" ::: "memory");
            __builtin_amdgcn_s_barrier();                        // #2: publish
            __builtin_amdgcn_sched_barrier(0);
        }
    }

    // ---- l reduction
#pragma unroll
    for (int jb = 0; jb < 8; ++jb) {
        float v = lpart[jb];
        v += __shfl_xor(v, 16, 64);
        v += __shfl_xor(v, 32, 64);
        lpart[jb] = v;
    }
    if (lane < 16) {
#pragma unroll
        for (int jb = 0; jb < 8; ++jb)
            lred[w][jb * 16 + l15] = lpart[jb];
    }
    __syncthreads();
    if (tid < 128) {
        float s = lred[0][tid] + lred[1][tid] + lred[2][tid] + lred[3][tid];
        lbuf[((size_t)sp * 4 + b) * N_PIX + j0 + tid] = s;
    }

    // ---- A partial store (bf16, unnormalized)
    unsigned short* Ab = Abuf + ((size_t)sp * 4 + b) * 256 * N_PIX;
#pragma unroll
    for (int cb = 0; cb < 4; ++cb) {
        int c = w * 64 + cb * 16 + quad * 4;
#pragma unroll
        for (int jb = 0; jb < 8; ++jb) {
            int j = j0 + jb * 16 + l15;
#pragma unroll
            for (int r = 0; r < 4; ++r)
                Ab[(size_t)(c + r) * N_PIX + j] = f2bf(acc[cb][jb][r]);
        }
    }
}

// ---------------------------------------------------------------------------
// combine: out = x + g * (sum_s A_s) / (sum_s l_s);  A is bf16.
// ---------------------------------------------------------------------------
__global__ __launch_bounds__(256) void combine_kernel(
    const unsigned short* __restrict__ A, const float* __restrict__ L,
    const float* __restrict__ x, const float* __restrict__ gamma,
    float* __restrict__ out, int split)
{
    const size_t CH = (size_t)4 * 256 * N_PIX;
    size_t flat = ((size_t)blockIdx.x * 256 + threadIdx.x) * 8;
    int j = (int)(flat & (N_PIX - 1));
    int b = (int)(flat >> 20);

    float a[8] = {0.f, 0.f, 0.f, 0.f, 0.f, 0.f, 0.f, 0.f};
    float l[8] = {0.f, 0.f, 0.f, 0.f, 0.f, 0.f, 0.f, 0.f};
    for (int s = 0; s < split; ++s) {
        ushort4 av0 = *(const ushort4*)&A[flat + (size_t)s * CH];
        ushort4 av1 = *(const ushort4*)&A[flat + (size_t)s * CH + 4];
        a[0] += bf2f(av0.x); a[1] += bf2f(av0.y); a[2] += bf2f(av0.z); a[3] += bf2f(av0.w);
        a[4] += bf2f(av1.x); a[5] += bf2f(av1.y); a[6] += bf2f(av1.z); a[7] += bf2f(av1.w);
        float4 l0 = *(const float4*)&L[((size_t)s * 4 + b) * N_PIX + j];
        float4 l1 = *(const float4*)&L[((size_t)s * 4 + b) * N_PIX + j + 4];
        l[0] += l0.x; l[1] += l0.y; l[2] += l0.z; l[3] += l0.w;
        l[4] += l1.x; l[5] += l1.y; l[6] += l1.z; l[7] += l1.w;
    }
    float g = gamma[0];
    float4 x0 = *(const float4*)&x[flat];
    float4 x1 = *(const float4*)&x[flat + 4];
    float4 o0, o1;
    o0.x = x0.x + g * a[0] / l[0];
    o0.y = x0.y + g * a[1] / l[1];
    o0.z = x0.z + g * a[2] / l[2];
    o0.w = x0.w + g * a[3] / l[3];
    o1.x = x1.x + g * a[4] / l[4];
    o1.y = x1.y + g * a[5] / l[5];
    o1.z = x1.z + g * a[6] / l[6];
    o1.w = x1.w + g * a[7] / l[7];
    *(float4*)&out[flat]     = o0;
    *(float4*)&out[flat + 4] = o1;
}

// ---------------------------------------------------------------------------
extern "C" void kernel_launch(void* const* d_in, const int* in_sizes, int n_in,
                              void* d_out, int out_size, void* d_ws, size_t ws_size,
                              hipStream_t stream)
{
    const float* x     = (const float*)d_in[0];
    const float* wq    = (const float*)d_in[1];
    const float* bq    = (const float*)d_in[2];
    const float* wk    = (const float*)d_in[3];
    const float* bk    = (const float*)d_in[4];
    const float* wv    = (const float*)d_in[5];
    const float* bv    = (const float*)d_in[6];
    const float* gamma = (const float*)d_in[7];
    float* out = (float*)d_out;

    const size_t szQTel  = (size_t)4 * N_PIX * 32;        // elements (ushort)
    const size_t szVBFel = (size_t)4 * 256 * N_PIX;
    const size_t szXBFel = (size_t)4 * N_PIX * 256;
    const size_t szWel   = (size_t)72 * 320 * 32;
    const size_t fixedB  = (2 * szQTel + szVBFel + szXBFel + szWel + 256) * 2;

    // split=8 -> 1024 attn blocks = 3/CU (LDS-capped); falls back 8->4->2
    // if the workspace can't hold split x 8 MB of bf16 partials.
    int split = 8;
    while (split > 1) {
        size_t need = fixedB
                    + (size_t)split * 4 * 256 * N_PIX * 2    // A bf16
                    + (size_t)split * 4 * N_PIX * 4;         // l fp32
        if (need <= ws_size) break;
        split >>= 1;
    }

    unsigned short* Abuf = (unsigned short*)d_ws;
    float* lbuf = (float*)(Abuf + (size_t)split * 4 * 256 * N_PIX);
    unsigned short* qt    = (unsigned short*)(lbuf + (size_t)split * 4 * N_PIX);
    unsigned short* kt    = qt + szQTel;
    unsigned short* vbf   = kt + szQTel;
    unsigned short* xbf   = vbf + szVBFel;
    unsigned short* wAll  = xbf + szXBFel;
    unsigned short* zpage = wAll + szWel;                  // 256 ushorts of 0

    prep_kernel<<<dim3(N_PIX / 64, 4, 5), 256, 0, stream>>>(
        x, xbf, wq, wk, wv, wAll, zpage);

    conv_gemm_v9<<<dim3(HW, 2, 4), 256, 0, stream>>>(
        xbf, wAll, bq, bk, bv, zpage, vbf, qt, kt);

    fused_attn_mfma<<<dim3(N_PIX / 128, 4, split), 256, 0, stream>>>(
        qt, kt, vbf, Abuf, lbuf, N_PIX / split);

    combine_kernel<<<dim3((4 * 256 * N_PIX) / (256 * 8)), 256, 0, stream>>>(
        Abuf, lbuf, x, gamma, out, split);
}

// Round 16
// 173.653 us; speedup vs baseline: 1.0508x; 1.0508x over previous
//
#include <hip/hip_runtime.h>
#include <cstddef>

#define N_PIX 4096
#define HW 64
#define LOG2E 1.4426950408889634f
#define SHIFT2 28.8539008177793f   // 20 * log2(e)

typedef __attribute__((ext_vector_type(8))) short bf16x8;
typedef __attribute__((ext_vector_type(4))) float f32x4;
typedef unsigned int u32;

static __device__ __forceinline__ unsigned short f2bf(float f) {
    union { float f; unsigned u; } v; v.f = f;
    unsigned r = v.u + 0x7fffu + ((v.u >> 16) & 1u);   // RNE
    return (unsigned short)(r >> 16);
}
static __device__ __forceinline__ float bf2f(unsigned short s) {
    union { unsigned u; float f; } v; v.u = (unsigned)s << 16;
    return v.f;
}
// (bf16(hi)<<16)|bf16(lo), truncating: one v_perm_b32
static __device__ __forceinline__ unsigned pack_bf16_trunc(float lo, float hi) {
    union { float f; unsigned u; } a, b; a.f = hi; b.f = lo;
    return __builtin_amdgcn_perm(a.u, b.u, 0x07060302u);
}
// async global->LDS, 16 B per lane; LDS dest is WAVE-UNIFORM base + lane*16
static __device__ __forceinline__ void gll16(const void* g, void* l) {
    __builtin_amdgcn_global_load_lds(
        (const __attribute__((address_space(1))) u32*)g,
        (__attribute__((address_space(3))) u32*)l, 16, 0, 0);
}

// ---------------------------------------------------------------------------
// prep: z<4  -> x [b][256 ci][4096 px] fp32 -> xbf [b][4096 px][256 ci] bf16
//       z==4 -> weights -> wAll [kb][320 rows][32 kin] bf16 + zero page.
// ---------------------------------------------------------------------------
__global__ __launch_bounds__(256) void prep_kernel(
    const float* __restrict__ x, unsigned short* __restrict__ xbf,
    const float* __restrict__ wq, const float* __restrict__ wk,
    const float* __restrict__ wv, unsigned short* __restrict__ wAll,
    unsigned short* __restrict__ zp)
{
    const int tid = threadIdx.x;
    if (blockIdx.z < 4) {
        __shared__ unsigned short Ts[64][72];
        const int px0 = blockIdx.x * 64, ci0 = blockIdx.y * 64, b = blockIdx.z;
        const float* xb = x + ((size_t)b * 256 + ci0) * N_PIX;

#pragma unroll
        for (int r = 0; r < 4; ++r) {
            int c = r * 16 + (tid >> 4);
            int p4 = (tid & 15) * 4;
            float4 v = *(const float4*)&xb[(size_t)c * N_PIX + px0 + p4];
            Ts[c][p4 + 0] = f2bf(v.x);
            Ts[c][p4 + 1] = f2bf(v.y);
            Ts[c][p4 + 2] = f2bf(v.z);
            Ts[c][p4 + 3] = f2bf(v.w);
        }
        __syncthreads();
#pragma unroll
        for (int r = 0; r < 2; ++r) {
            int id = tid * 2 + r;
            int p = id >> 3, c8 = (id & 7) * 8;
            ushort4 lo, hi;
            lo.x = Ts[c8 + 0][p]; lo.y = Ts[c8 + 1][p];
            lo.z = Ts[c8 + 2][p]; lo.w = Ts[c8 + 3][p];
            hi.x = Ts[c8 + 4][p]; hi.y = Ts[c8 + 5][p];
            hi.z = Ts[c8 + 6][p]; hi.w = Ts[c8 + 7][p];
            size_t off = ((size_t)b * N_PIX + px0 + p) * 256 + ci0 + c8;
            *(ushort4*)&xbf[off]     = lo;
            *(ushort4*)&xbf[off + 4] = hi;
        }
    } else {
        const int f = blockIdx.y * 64 + blockIdx.x;        // 0..255
#pragma unroll
        for (int base = 0; base < 2; ++base) {
            int gid = base * 65536 + f * 256 + tid;
            if (gid < 256) zp[gid] = 0;
            if (gid >= 72 * 320 * 4) continue;
            int part = gid & 3;
            int m = (gid >> 2) % 320;
            int kb = gid / 1280;
            int t = kb >> 3;
            int ci0 = (kb & 7) * 32 + part * 8;
            const float* src; int co; float sc = 1.f;
            if (m < 256)      { src = wv; co = m; }
            else if (m < 288) { src = wq; co = m - 256; sc = LOG2E; }
            else              { src = wk; co = m - 288; }
            ushort4 lo, hi;
            lo.x = f2bf(sc * src[((size_t)co * 256 + ci0 + 0) * 9 + t]);
            lo.y = f2bf(sc * src[((size_t)co * 256 + ci0 + 1) * 9 + t]);
            lo.z = f2bf(sc * src[((size_t)co * 256 + ci0 + 2) * 9 + t]);
            lo.w = f2bf(sc * src[((size_t)co * 256 + ci0 + 3) * 9 + t]);
            hi.x = f2bf(sc * src[((size_t)co * 256 + ci0 + 4) * 9 + t]);
            hi.y = f2bf(sc * src[((size_t)co * 256 + ci0 + 5) * 9 + t]);
            hi.z = f2bf(sc * src[((size_t)co * 256 + ci0 + 6) * 9 + t]);
            hi.w = f2bf(sc * src[((size_t)co * 256 + ci0 + 7) * 9 + t]);
            size_t off = ((size_t)kb * 320 + m) * 32 + part * 8;
            *(ushort4*)&wAll[off]     = lo;
            *(ushort4*)&wAll[off + 4] = hi;
        }
    }
}

// ---------------------------------------------------------------------------
// Conv implicit GEMM v9 (best conv measured): 64-px tile, 512 blocks = 2/CU,
// 3-buf gll-DMA pipeline, counted vmcnt(4/3), raw s_barrier, 72-step K-loop
// fully unrolled.
// ---------------------------------------------------------------------------
__global__ __launch_bounds__(256, 2) void conv_gemm_v9(
    const unsigned short* __restrict__ xbf, const unsigned short* __restrict__ wAll,
    const float* __restrict__ bq, const float* __restrict__ bk,
    const float* __restrict__ bv, const unsigned short* __restrict__ zpage,
    unsigned short* __restrict__ vbf, unsigned short* __restrict__ qt,
    unsigned short* __restrict__ kt)
{
    __shared__ unsigned short Bl[3 * 7168];   // 3 bufs x 14336 B = 43 KB

    const int tid = threadIdx.x;
    const int w = tid >> 6, lane = tid & 63, quad = lane >> 4, l15 = lane & 15;
    const int y = blockIdx.x, rh = blockIdx.y, b = blockIdx.z;
    const int rg = w >> 1;          // 80-row group within the 160
    const int pxh = w & 1;          // 32-px half

    const unsigned short* xb = xbf + (size_t)b * N_PIX * 256;
    const unsigned short* aSrc = wAll + (size_t)rh * 160 * 32;   // +kb*10240

    auto stage = [&](int kb, int buf) {
        const int t_ = kb >> 3;
        const int ty = t_ / 3;
        const int dy = ty - 1, dx = t_ - ty * 3 - 1;
        const int gy = y + dy;
        const bool rowOK = ((unsigned)gy < 64u);
        const int ci0 = (kb & 7) * 32;
        const unsigned short* aS = aSrc + (size_t)kb * 10240;
        unsigned short* tile = &Bl[buf * 7168];
#pragma unroll
        for (int r = 0; r < 4; ++r) {
            const int c = r * 4 + w;
            if (r == 3 && w >= 2) continue;      // wave-uniform skip
            if (c < 10) {
                int o = c * 1024 + lane * 16;
                int u = o ^ (((o >> 7) & 7) << 4);
                gll16(aS + (u >> 1), tile + c * 512);
            } else {
                int o = (c - 10) * 1024 + lane * 16;
                int u = o ^ (((o >> 7) & 7) << 4);
                int px = u >> 6, k16 = (u >> 4) & 3;
                int gx = px + dx;
                const unsigned short* src =
                    (rowOK && (unsigned)gx < 64u)
                        ? xb + ((size_t)(gy * 64 + gx) * 256 + ci0 + k16 * 8)
                        : zpage;
                gll16(src, tile + 5120 + (c - 10) * 512);
            }
        }
    };

    f32x4 acc[5][2];
#pragma unroll
    for (int cb = 0; cb < 5; ++cb)
#pragma unroll
        for (int jb = 0; jb < 2; ++jb) acc[cb][jb] = (f32x4){0.f, 0.f, 0.f, 0.f};

    // ---- prologue: fill pipeline 2 deep
    stage(0, 0);
    stage(1, 1);
    if (w < 2) asm volatile("s_waitcnt vmcnt(4)" ::: "memory");
    else       asm volatile("s_waitcnt vmcnt(3)" ::: "memory");
    __builtin_amdgcn_s_barrier();
    __builtin_amdgcn_sched_barrier(0);

#pragma unroll
    for (int kb = 0; kb < 72; ++kb) {
        const int buf = kb % 3;
        const int pb  = (kb + 2) % 3;
        const bool more2 = (kb + 2 < 72);
        const bool more1 = (kb + 1 < 72);
        if (more2) stage(kb + 2, pb);

        // ---- frag reads from buf (swizzled), then MFMA
        const int bb = buf * 7168;
        bf16x8 af[5], bfr[2];
#pragma unroll
        for (int cb = 0; cb < 5; ++cb) {
            int sr = rg * 80 + cb * 16 + l15;
            int u = sr * 64 + quad * 16;
            u ^= ((u >> 7) & 7) << 4;
            af[cb] = *(const bf16x8*)&Bl[bb + (u >> 1)];
        }
#pragma unroll
        for (int jb = 0; jb < 2; ++jb) {
            int px = pxh * 32 + jb * 16 + l15;
            int u = px * 64 + quad * 16;
            u ^= ((u >> 7) & 7) << 4;
            bfr[jb] = *(const bf16x8*)&Bl[bb + 5120 + (u >> 1)];
        }
        __builtin_amdgcn_s_setprio(1);
#pragma unroll
        for (int cb = 0; cb < 5; ++cb)
#pragma unroll
            for (int jb = 0; jb < 2; ++jb)
                acc[cb][jb] = __builtin_amdgcn_mfma_f32_16x16x32_bf16(
                    af[cb], bfr[jb], acc[cb][jb], 0, 0, 0);
        __builtin_amdgcn_s_setprio(0);

        // ---- counted wait: kb+1 landed, kb+2 stays in flight
        if (more2) {
            if (w < 2) asm volatile("s_waitcnt vmcnt(4)" ::: "memory");
            else       asm volatile("s_waitcnt vmcnt(3)" ::: "memory");
        } else if (more1) {
            asm volatile("s_waitcnt vmcnt(0)" ::: "memory");
        }
        if (more1) {
            __builtin_amdgcn_s_barrier();
            __builtin_amdgcn_sched_barrier(0);
        }
    }

    // ---- epilogue: rows <256 -> V, 256..287 -> Q (log2e-scaled), 288.. -> K
#pragma unroll
    for (int cb = 0; cb < 5; ++cb) {
        int cBase = rh * 160 + rg * 80 + cb * 16 + quad * 4;
#pragma unroll
        for (int r = 0; r < 4; ++r) {
            int c = cBase + r;
            if (c < 256) {
                float bias = bv[c];
#pragma unroll
                for (int jb = 0; jb < 2; ++jb) {
                    int px = y * 64 + pxh * 32 + jb * 16 + l15;
                    vbf[((size_t)b * 256 + c) * N_PIX + px] = f2bf(acc[cb][jb][r] + bias);
                }
            } else if (c < 288) {
                float bias = bq[c - 256] * LOG2E;
#pragma unroll
                for (int jb = 0; jb < 2; ++jb) {
                    int px = y * 64 + pxh * 32 + jb * 16 + l15;
                    qt[((size_t)b * N_PIX + px) * 32 + (c - 256)] = f2bf(acc[cb][jb][r] + bias);
                }
            } else {
                float bias = bk[c - 288];
#pragma unroll
                for (int jb = 0; jb < 2; ++jb) {
                    int px = y * 64 + pxh * 32 + jb * 16 + l15;
                    kt[((size_t)b * N_PIX + px) * 32 + (c - 288)] = f2bf(acc[cb][jb][r] + bias);
                }
            }
        }
    }
}

// ---------------------------------------------------------------------------
// MFMA flash attention v6 (best attn measured within this structure,
// ~46.8us): j=128, single Pfrag (16 KB) + 2 barriers/iter, per-wave-private
// coalesced V DMA (gll16 + XOR swizzle), counted in-wave vmcnt (never
// drained by barriers), no setprio.  2 blocks/CU; all occupancy escapes
// measured dead (regs-spill / LDS-noop / split8-write-regression).
// ---------------------------------------------------------------------------
__global__ __launch_bounds__(256, 2) void fused_attn_mfma(
    const unsigned short* __restrict__ qt, const unsigned short* __restrict__ kt,
    const unsigned short* __restrict__ vbf,
    unsigned short* __restrict__ Abuf, float* __restrict__ lbuf, int iRange)
{
    const int tid  = threadIdx.x;
    const int w    = tid >> 6;
    const int lane = tid & 63;
    const int quad = lane >> 4;
    const int l15  = lane & 15;
    const int j0   = blockIdx.x * 128;
    const int b    = blockIdx.y;
    const int sp   = blockIdx.z;
    const int iBeg = sp * iRange;
    const int NI   = iRange / 64;

    const unsigned short* qtb = qt + (size_t)b * N_PIX * 32;
    const unsigned short* ktb = kt + (size_t)b * N_PIX * 32;
    const unsigned short* vb  = vbf + ((size_t)b * 256 + w * 64) * N_PIX;

    __shared__ unsigned Pfrag[4096];             // 16 KB single buffer
    __shared__ unsigned short Vl[4][2][2048];    // 32 KB: per-wave 2x4KB V slices
    __shared__ float lred[4][128];               // 2 KB  -> total 50 KB

    bf16x8 kf[8];
#pragma unroll
    for (int jb = 0; jb < 8; ++jb)
        kf[jb] = *(const bf16x8*)&ktb[((size_t)(j0 + jb * 16 + l15)) * 32 + quad * 8];

    f32x4 acc[4][8];
#pragma unroll
    for (int cb = 0; cb < 4; ++cb)
#pragma unroll
        for (int jb = 0; jb < 8; ++jb)
            acc[cb][jb] = (f32x4){0.f, 0.f, 0.f, 0.f};

    float lpart[8] = {0.f, 0.f, 0.f, 0.f, 0.f, 0.f, 0.f, 0.f};

    const int wFrag = w >> 1;
    const int wL    = ((w & 1) << 5) + ((quad >> 1) << 4) + l15;
    const int wEl2  = (quad & 1) << 1;   // dword offset 0 or 2

    // wave w stages V rows [w*64,+64) x cols [c0,+32) (4 KB) into Vl[w][vbuf];
    // XOR swizzle on SOURCE offset (gll dest is linear), same XOR on read.
    auto stageV = [&](int c0, int vbuf) {
#pragma unroll
        for (int r = 0; r < 4; ++r) {
            int o = r * 1024 + lane * 16;
            int u = o ^ (((o >> 7) & 7) << 4);
            const unsigned short* src =
                vb + (size_t)(u >> 6) * N_PIX + c0 + ((u & 63) >> 1);
            gll16(src, &Vl[w][vbuf][r * 512]);
        }
    };
    auto readVa = [&](int vbuf, bf16x8 (&va)[4]) {
#pragma unroll
        for (int cb = 0; cb < 4; ++cb) {
            int o = (cb * 16 + l15) * 64 + quad * 16;
            int u = o ^ (((o >> 7) & 7) << 4);
            va[cb] = *(const bf16x8*)&Vl[w][vbuf][u >> 1];
        }
    };

    auto s_phase = [&](bf16x8 qa) {
#pragma unroll
        for (int jb = 0; jb < 8; ++jb) {
            f32x4 s = __builtin_amdgcn_mfma_f32_16x16x32_bf16(
                qa, kf[jb], (f32x4){-SHIFT2, -SHIFT2, -SHIFT2, -SHIFT2}, 0, 0, 0);
            float p0 = __builtin_amdgcn_exp2f(s[0]);
            float p1 = __builtin_amdgcn_exp2f(s[1]);
            float p2 = __builtin_amdgcn_exp2f(s[2]);
            float p3 = __builtin_amdgcn_exp2f(s[3]);
            lpart[jb] += (p0 + p1) + (p2 + p3);
            unsigned u0 = pack_bf16_trunc(p0, p1);
            unsigned u1 = pack_bf16_trunc(p2, p3);
            unsigned base = (((jb << 1) + wFrag) * 64 + wL) * 4 + wEl2;
            Pfrag[base]     = u0;
            Pfrag[base + 1] = u1;
        }
    };

    auto load_qa = [&](int i0) {
        return *(const bf16x8*)&qtb[((size_t)(i0 + w * 16 + l15)) * 32 + quad * 8];
    };

    // ---- prologue: V(iter0) DMA, S(0) -> Pfrag, barrier
    stageV(iBeg, 0);
    stageV(iBeg + 32, 1);
    s_phase(load_qa(iBeg));
    asm volatile("s_waitcnt lgkmcnt(0)" ::: "memory");
    __builtin_amdgcn_s_barrier();
    __builtin_amdgcn_sched_barrier(0);

    for (int n = 0; n < NI; ++n) {
        const bool hasN = (n + 1 < NI);
        const int inext = iBeg + (n + 1) * 64;
        bf16x8 qaN;
        if (hasN) qaN = load_qa(inext);

        bf16x8 pb[8], va[4];

        // ---- ks = 0: consume Vl[w][0], refill with V(n+1, ks0)
#pragma unroll
        for (int jb = 0; jb < 8; ++jb)
            pb[jb] = *(const bf16x8*)&Pfrag[((jb << 1) * 64 + lane) * 4];
        if (hasN) asm volatile("s_waitcnt vmcnt(5)" ::: "memory");   // A landed (B4+qa1 left)
        else      asm volatile("s_waitcnt vmcnt(4)" ::: "memory");   // A landed (B4 left)
        __builtin_amdgcn_sched_barrier(0);
        readVa(0, va);
        asm volatile("s_waitcnt lgkmcnt(0)" ::: "memory");           // reads done pre-overwrite
        __builtin_amdgcn_sched_barrier(0);
        if (hasN) stageV(inext, 0);
#pragma unroll
        for (int cb = 0; cb < 4; ++cb)
#pragma unroll
            for (int jb = 0; jb < 8; ++jb)
                acc[cb][jb] = __builtin_amdgcn_mfma_f32_16x16x32_bf16(
                    va[cb], pb[jb], acc[cb][jb], 0, 0, 0);

        // ---- ks = 1: consume Vl[w][1], refill with V(n+1, ks1)
#pragma unroll
        for (int jb = 0; jb < 8; ++jb)
            pb[jb] = *(const bf16x8*)&Pfrag[(((jb << 1) + 1) * 64 + lane) * 4];
        if (hasN) asm volatile("s_waitcnt vmcnt(5)" ::: "memory");   // B landed (qa1+A'4 left)
        else      asm volatile("s_waitcnt vmcnt(0)" ::: "memory");
        __builtin_amdgcn_sched_barrier(0);
        readVa(1, va);
        asm volatile("s_waitcnt lgkmcnt(0)" ::: "memory");
        __builtin_amdgcn_sched_barrier(0);
        if (hasN) stageV(inext + 32, 1);
#pragma unroll
        for (int cb = 0; cb < 4; ++cb)
#pragma unroll
            for (int jb = 0; jb < 8; ++jb)
                acc[cb][jb] = __builtin_amdgcn_mfma_f32_16x16x32_bf16(
                    va[cb], pb[jb], acc[cb][jb], 0, 0, 0);

        // ---- release Pfrag, then S(n+1) -> Pfrag, then publish
        if (hasN) {
            asm volatile("s_waitcnt lgkmcnt(0)" ::: "memory");   // all P reads done
            __builtin_amdgcn_s_barrier();                        // #1: release
            __builtin_amdgcn_sched_barrier(0);
            s_phase(qaN);
            asm volatile("s_waitcnt lgkmcnt(0)" ::: "memory");
            __builtin_amdgcn_s_barrier();                        // #2: publish
            __builtin_amdgcn_sched_barrier(0);
        }
    }

    // ---- l reduction
#pragma unroll
    for (int jb = 0; jb < 8; ++jb) {
        float v = lpart[jb];
        v += __shfl_xor(v, 16, 64);
        v += __shfl_xor(v, 32, 64);
        lpart[jb] = v;
    }
    if (lane < 16) {
#pragma unroll
        for (int jb = 0; jb < 8; ++jb)
            lred[w][jb * 16 + l15] = lpart[jb];
    }
    __syncthreads();
    if (tid < 128) {
        float s = lred[0][tid] + lred[1][tid] + lred[2][tid] + lred[3][tid];
        lbuf[((size_t)sp * 4 + b) * N_PIX + j0 + tid] = s;
    }

    // ---- A partial store (bf16, unnormalized)
    unsigned short* Ab = Abuf + ((size_t)sp * 4 + b) * 256 * N_PIX;
#pragma unroll
    for (int cb = 0; cb < 4; ++cb) {
        int c = w * 64 + cb * 16 + quad * 4;
#pragma unroll
        for (int jb = 0; jb < 8; ++jb) {
            int j = j0 + jb * 16 + l15;
#pragma unroll
            for (int r = 0; r < 4; ++r)
                Ab[(size_t)(c + r) * N_PIX + j] = f2bf(acc[cb][jb][r]);
        }
    }
}

// ---------------------------------------------------------------------------
// combine: out = x + g * (sum_s A_s) / (sum_s l_s);  A is bf16.
// ---------------------------------------------------------------------------
__global__ __launch_bounds__(256) void combine_kernel(
    const unsigned short* __restrict__ A, const float* __restrict__ L,
    const float* __restrict__ x, const float* __restrict__ gamma,
    float* __restrict__ out, int split)
{
    const size_t CH = (size_t)4 * 256 * N_PIX;
    size_t flat = ((size_t)blockIdx.x * 256 + threadIdx.x) * 8;
    int j = (int)(flat & (N_PIX - 1));
    int b = (int)(flat >> 20);

    float a[8] = {0.f, 0.f, 0.f, 0.f, 0.f, 0.f, 0.f, 0.f};
    float l[8] = {0.f, 0.f, 0.f, 0.f, 0.f, 0.f, 0.f, 0.f};
    for (int s = 0; s < split; ++s) {
        ushort4 av0 = *(const ushort4*)&A[flat + (size_t)s * CH];
        ushort4 av1 = *(const ushort4*)&A[flat + (size_t)s * CH + 4];
        a[0] += bf2f(av0.x); a[1] += bf2f(av0.y); a[2] += bf2f(av0.z); a[3] += bf2f(av0.w);
        a[4] += bf2f(av1.x); a[5] += bf2f(av1.y); a[6] += bf2f(av1.z); a[7] += bf2f(av1.w);
        float4 l0 = *(const float4*)&L[((size_t)s * 4 + b) * N_PIX + j];
        float4 l1 = *(const float4*)&L[((size_t)s * 4 + b) * N_PIX + j + 4];
        l[0] += l0.x; l[1] += l0.y; l[2] += l0.z; l[3] += l0.w;
        l[4] += l1.x; l[5] += l1.y; l[6] += l1.z; l[7] += l1.w;
    }
    float g = gamma[0];
    float4 x0 = *(const float4*)&x[flat];
    float4 x1 = *(const float4*)&x[flat + 4];
    float4 o0, o1;
    o0.x = x0.x + g * a[0] / l[0];
    o0.y = x0.y + g * a[1] / l[1];
    o0.z = x0.z + g * a[2] / l[2];
    o0.w = x0.w + g * a[3] / l[3];
    o1.x = x1.x + g * a[4] / l[4];
    o1.y = x1.y + g * a[5] / l[5];
    o1.z = x1.z + g * a[6] / l[6];
    o1.w = x1.w + g * a[7] / l[7];
    *(float4*)&out[flat]     = o0;
    *(float4*)&out[flat + 4] = o1;
}

// ---------------------------------------------------------------------------
extern "C" void kernel_launch(void* const* d_in, const int* in_sizes, int n_in,
                              void* d_out, int out_size, void* d_ws, size_t ws_size,
                              hipStream_t stream)
{
    const float* x     = (const float*)d_in[0];
    const float* wq    = (const float*)d_in[1];
    const float* bq    = (const float*)d_in[2];
    const float* wk    = (const float*)d_in[3];
    const float* bk    = (const float*)d_in[4];
    const float* wv    = (const float*)d_in[5];
    const float* bv    = (const float*)d_in[6];
    const float* gamma = (const float*)d_in[7];
    float* out = (float*)d_out;

    const size_t szQTel  = (size_t)4 * N_PIX * 32;        // elements (ushort)
    const size_t szVBFel = (size_t)4 * 256 * N_PIX;
    const size_t szXBFel = (size_t)4 * N_PIX * 256;
    const size_t szWel   = (size_t)72 * 320 * 32;
    const size_t fixedB  = (2 * szQTel + szVBFel + szXBFel + szWel + 256) * 2;

    // split=4 (measured optimum; split=8 doubled partial traffic, regressed)
    int split = 4;
    while (split > 1) {
        size_t need = fixedB
                    + (size_t)split * 4 * 256 * N_PIX * 2    // A bf16
                    + (size_t)split * 4 * N_PIX * 4;         // l fp32
        if (need <= ws_size) break;
        split >>= 1;
    }

    unsigned short* Abuf = (unsigned short*)d_ws;
    float* lbuf = (float*)(Abuf + (size_t)split * 4 * 256 * N_PIX);
    unsigned short* qt    = (unsigned short*)(lbuf + (size_t)split * 4 * N_PIX);
    unsigned short* kt    = qt + szQTel;
    unsigned short* vbf   = kt + szQTel;
    unsigned short* xbf   = vbf + szVBFel;
    unsigned short* wAll  = xbf + szXBFel;
    unsigned short* zpage = wAll + szWel;                  // 256 ushorts of 0

    prep_kernel<<<dim3(N_PIX / 64, 4, 5), 256, 0, stream>>>(
        x, xbf, wq, wk, wv, wAll, zpage);

    conv_gemm_v9<<<dim3(HW, 2, 4), 256, 0, stream>>>(
        xbf, wAll, bq, bk, bv, zpage, vbf, qt, kt);

    fused_attn_mfma<<<dim3(N_PIX / 128, 4, split), 256, 0, stream>>>(
        qt, kt, vbf, Abuf, lbuf, N_PIX / split);

    combine_kernel<<<dim3((4 * 256 * N_PIX) / (256 * 8)), 256, 0, stream>>>(
        Abuf, lbuf, x, gamma, out, split);
}